// Round 4
// baseline (683.186 us; speedup 1.0000x reference)
//
#include <hip/hip_runtime.h>
#include <hip/hip_bf16.h>
#include <stdint.h>

typedef unsigned short ushortT;
typedef __bf16 bf16x8 __attribute__((ext_vector_type(8)));
typedef float f32x4 __attribute__((ext_vector_type(4)));
typedef unsigned short u16x8 __attribute__((ext_vector_type(8)));

#define N_TOK 131072
#define NSEG  256

__device__ __forceinline__ uint32_t f2bf(float f) {
  union { float f; uint32_t u; } c; c.f = f;
  uint32_t u = c.u;
  u += 0x7fffu + ((u >> 16) & 1u);   // RNE
  return u >> 16;
}
__device__ __forceinline__ float bf2f(uint32_t b) {
  union { uint32_t u; float f; } c; c.u = b << 16;
  return c.f;
}

// ---------------- prep kernels ----------------

// WT[n*Kd + k] = bf16(W[k*Nd + n]);  W is [Kd][Nd] row-major
__global__ void transpose_bf16_kernel(const float* __restrict__ W, ushortT* __restrict__ WT,
                                      int Kd, int Nd) {
  int i = blockIdx.x * 256 + threadIdx.x;
  if (i < Kd * Nd) {
    int n = i / Kd, k = i % Kd;
    WT[i] = (ushortT)f2bf(W[(size_t)k * Nd + n]);
  }
}

// weff[c*8+h] = sum_d Wk[c,h*128+d]*Wq[h,d] / sqrt(128),  c in [0,640)
__global__ void weff_kernel(const float* __restrict__ Wk, const float* __restrict__ Wq,
                            float* __restrict__ weff) {
  const int c = blockIdx.x;       // 640
  const int lane = threadIdx.x;   // 64
  const float rs = 0.08838834764831845f;
#pragma unroll
  for (int h = 0; h < 8; ++h) {
    float acc = Wk[(size_t)c * 1024 + h * 128 + lane] * Wq[h * 128 + lane]
              + Wk[(size_t)c * 1024 + h * 128 + 64 + lane] * Wq[h * 128 + 64 + lane];
#pragma unroll
    for (int off = 32; off >= 1; off >>= 1) acc += __shfl_xor(acc, off, 64);
    if (lane == 0) weff[c * 8 + h] = acc * rs;
  }
}

// ---------------- fused MLP chain ----------------
// One block = 128 token rows. LDS h-buffer [128][512] bf16 (swizzled), holds the
// current layer input. Each layer: MFMA phase reads ALL of h into acc (regs),
// barrier, epilogue writes h in place (or Z to global for the last layer), barrier.
// 8 waves; wave wv owns output cols [wv*64, wv*64+64).
//
// LDS swizzle (both write and read): byte(row, k) = row*1024 + ((k*2) ^ ((row&7)<<4))
// A-frag read (m97-verified fragment): row = rt*16 + (lane&15), 16B at k = kk*32 + (lane>>4)*8
// B-frag from global WT[col][K]: col = wv*64 + ct*16 + (lane&15), 16B at k = kk*32 + (lane>>4)*8
// C/D layout: col = colbase + (lane&15), row = rowbase + (lane>>4)*4 + r

template <int K, bool RELU, bool BIAS, bool TO_GLOBAL>
__device__ __forceinline__ void layer_fn(char* hb, const ushortT* __restrict__ WT,
                                         const float* __restrict__ bias,
                                         ushortT* __restrict__ Zblk,
                                         int wv, int lane) {
  constexpr int KS = K / 32;
  const int q  = lane >> 4;
  const int lr = lane & 15;
  const int xk = lane & 7;   // (row & 7) for all A-frag rows (rt*16 + lr)

  f32x4 acc[8][4];
#pragma unroll
  for (int i = 0; i < 8; ++i)
#pragma unroll
    for (int j = 0; j < 4; ++j) acc[i][j] = 0.f;

  const ushortT* wp[4];
#pragma unroll
  for (int ct = 0; ct < 4; ++ct)
    wp[ct] = WT + (size_t)(wv * 64 + ct * 16 + lr) * K + q * 8;

  bf16x8 b0[4], b1[4];
#pragma unroll
  for (int ct = 0; ct < 4; ++ct) b0[ct] = *(const bf16x8*)(wp[ct]);

#pragma unroll 1
  for (int kk = 0; kk < KS; kk += 2) {
    bf16x8 a[8];
#pragma unroll
    for (int rt = 0; rt < 8; ++rt)
      a[rt] = *(const bf16x8*)(hb + (rt * 16 + lr) * 1024 + (((kk * 4 + q) ^ xk) << 4));
#pragma unroll
    for (int ct = 0; ct < 4; ++ct) {
      b1[ct] = *(const bf16x8*)(wp[ct] + (kk + 1) * 32);
#pragma unroll
      for (int rt = 0; rt < 8; ++rt)
        acc[rt][ct] = __builtin_amdgcn_mfma_f32_16x16x32_bf16(a[rt], b0[ct], acc[rt][ct], 0, 0, 0);
    }
#pragma unroll
    for (int rt = 0; rt < 8; ++rt)
      a[rt] = *(const bf16x8*)(hb + (rt * 16 + lr) * 1024 + ((((kk + 1) * 4 + q) ^ xk) << 4));
#pragma unroll
    for (int ct = 0; ct < 4; ++ct) {
      if (kk + 2 < KS) b0[ct] = *(const bf16x8*)(wp[ct] + (kk + 2) * 32);
#pragma unroll
      for (int rt = 0; rt < 8; ++rt)
        acc[rt][ct] = __builtin_amdgcn_mfma_f32_16x16x32_bf16(a[rt], b1[ct], acc[rt][ct], 0, 0, 0);
    }
  }

  __syncthreads();   // all reads of h complete before overwrite

#pragma unroll
  for (int ct = 0; ct < 4; ++ct) {
    const int col = wv * 64 + ct * 16 + lr;
    const float bvv = BIAS ? bias[col] : 0.f;
#pragma unroll
    for (int rt = 0; rt < 8; ++rt) {
#pragma unroll
      for (int r = 0; r < 4; ++r) {
        const int row = rt * 16 + q * 4 + r;
        float v = acc[rt][ct][r] + bvv;
        if (RELU) v = fmaxf(v, 0.f);
        const ushortT hv = (ushortT)f2bf(v);
        if (TO_GLOBAL) Zblk[(size_t)row * 512 + col] = hv;
        else *(ushortT*)(hb + row * 1024 + ((col * 2) ^ ((row & 7) << 4))) = hv;
      }
    }
  }
  __syncthreads();
}

__global__ __launch_bounds__(512, 2)
void fused_chain_kernel(const float* __restrict__ X,
                        const ushortT* __restrict__ W1T, const float* __restrict__ b1,
                        const ushortT* __restrict__ W2T, const float* __restrict__ b2,
                        const ushortT* __restrict__ W3T, const float* __restrict__ b3,
                        const ushortT* __restrict__ WrT, ushortT* __restrict__ Z) {
  __shared__ char hbuf[128 * 1024];   // [128 rows][512 cols] bf16, swizzled

  const int t = (int)threadIdx.x;
  const int wv = t >> 6, lane = t & 63;
  const int blk = (int)blockIdx.x;

  // ---- stage X (128 rows x 128 cols f32 -> bf16, swizzled) ----
  {
    const float4* Xs = (const float4*)(X + (size_t)blk * 128 * 128);
    const int row = t >> 2, sub = t & 3;
    char* rowp = hbuf + row * 1024;
    const int xr = (row & 7) << 4;
#pragma unroll
    for (int j = 0; j < 8; ++j) {
      const float4 v = Xs[row * 32 + sub * 8 + j];
      uint2 pk;
      pk.x = f2bf(v.x) | (f2bf(v.y) << 16);
      pk.y = f2bf(v.z) | (f2bf(v.w) << 16);
      *(uint2*)(rowp + ((sub * 64 + j * 8) ^ xr)) = pk;
    }
  }
  __syncthreads();

  ushortT* Zblk = Z + (size_t)blk * 128 * 512;
  layer_fn<128, true,  true,  false>(hbuf, W1T, b1, nullptr, wv, lane);
  layer_fn<512, true,  true,  false>(hbuf, W2T, b2, nullptr, wv, lane);
  layer_fn<512, true,  true,  false>(hbuf, W3T, b3, nullptr, wv, lane);
  layer_fn<512, false, false, true >(hbuf, WrT, nullptr, Zblk, wv, lane);
}

// ---------------- segment prefix-mean scan with cross-chunk carry ----------------

__global__ __launch_bounds__(256)
void scan_kernel(const ushortT* __restrict__ z, ushortT* __restrict__ gout,
                 const int* __restrict__ seg, const float* __restrict__ br,
                 float* __restrict__ carry_sum, int* __restrict__ carry_cnt,
                 int c0, int rows) {
  const int s = (int)blockIdx.x;   // segment id
  const int t = (int)threadIdx.x;  // word (2 cols) owner

  int lo = c0, hi = c0 + rows;
  while (lo < hi) { int m = (lo + hi) >> 1; if (seg[m] < s) lo = m + 1; else hi = m; }
  const int beg = lo;
  hi = c0 + rows;
  while (lo < hi) { int m = (lo + hi) >> 1; if (seg[m] < s + 1) lo = m + 1; else hi = m; }
  const int end = lo;
  if (end <= beg) return;

  const float b0 = br[2 * t], b1v = br[2 * t + 1];
  float a0 = carry_sum[s * 512 + 2 * t];
  float a1 = carry_sum[s * 512 + 2 * t + 1];
  const int cntBase = carry_cnt[s];
  const uint32_t* __restrict__ zp = (const uint32_t*)z;
  uint32_t* __restrict__ gp = (uint32_t*)gout;

  constexpr int P = 16;
  uint32_t buf[P];
#pragma unroll
  for (int p = 0; p < P; ++p)
    buf[p] = (beg + p < end) ? zp[(size_t)(beg + p - c0) * 256 + t] : 0u;

  int base = beg;
  for (; base + 2 * P <= end; base += P) {
#pragma unroll
    for (int p = 0; p < P; ++p) {
      const int r = base + p;
      const uint32_t v = buf[p];
      buf[p] = zp[(size_t)(r + P - c0) * 256 + t];
      a0 += bf2f(v & 0xffffu);
      a1 += bf2f(v >> 16);
      const float inv = 1.0f / (float)(cntBase + r - beg + 1);
      const float g0 = fmaxf(fmaf(a0, inv, b0), 0.f);
      const float g1 = fmaxf(fmaf(a1, inv, b1v), 0.f);
      gp[(size_t)(r - c0) * 256 + t] = f2bf(g0) | (f2bf(g1) << 16);
    }
  }
  for (; base < end; base += P) {
#pragma unroll
    for (int p = 0; p < P; ++p) {
      const int r = base + p;
      if (r < end) {
        const uint32_t v = buf[p];
        buf[p] = (r + P < end) ? zp[(size_t)(r + P - c0) * 256 + t] : 0u;
        a0 += bf2f(v & 0xffffu);
        a1 += bf2f(v >> 16);
        const float inv = 1.0f / (float)(cntBase + r - beg + 1);
        const float g0 = fmaxf(fmaf(a0, inv, b0), 0.f);
        const float g1 = fmaxf(fmaf(a1, inv, b1v), 0.f);
        gp[(size_t)(r - c0) * 256 + t] = f2bf(g0) | (f2bf(g1) << 16);
      }
    }
  }

  carry_sum[s * 512 + 2 * t]     = a0;
  carry_sum[s * 512 + 2 * t + 1] = a1;
  if (t == 0) carry_cnt[s] = cntBase + (end - beg);
}

// ---------------- final: out[n,h] = X[n,:]@weff[0:128,h] + g[n,:]@weff[128:640,h] ----------------

__global__ __launch_bounds__(256)
void final_kernel(const float* __restrict__ X, const ushortT* __restrict__ g,
                  const float* __restrict__ weff, float* __restrict__ out, int rows) {
  const int t = (int)threadIdx.x;
  const int wv = t >> 6, lane = t & 63;

  float wx0[8], wx1[8], wg[8][8];
#pragma unroll
  for (int h = 0; h < 8; ++h) {
    wx0[h] = weff[(2 * lane) * 8 + h];
    wx1[h] = weff[(2 * lane + 1) * 8 + h];
  }
#pragma unroll
  for (int j = 0; j < 8; ++j)
#pragma unroll
    for (int h = 0; h < 8; ++h)
      wg[j][h] = weff[(128 + 8 * lane + j) * 8 + h];

  for (int row = (int)blockIdx.x * 4 + wv; row < rows; row += (int)gridDim.x * 4) {
    const float2 xv = *(const float2*)&X[(size_t)row * 128 + 2 * lane];
    const u16x8 gv = *(const u16x8*)&g[(size_t)row * 512 + 8 * lane];
    float pp[8];
#pragma unroll
    for (int h = 0; h < 8; ++h) pp[h] = xv.x * wx0[h] + xv.y * wx1[h];
#pragma unroll
    for (int j = 0; j < 8; ++j) {
      const float f = bf2f((uint32_t)gv[j]);
#pragma unroll
      for (int h = 0; h < 8; ++h) pp[h] = fmaf(f, wg[j][h], pp[h]);
    }
#pragma unroll
    for (int off = 32; off >= 1; off >>= 1) {
#pragma unroll
      for (int h = 0; h < 8; ++h) pp[h] += __shfl_xor(pp[h], off, 64);
    }
    if (lane == 0) {
#pragma unroll
      for (int h = 0; h < 8; ++h) out[(size_t)row * 8 + h] = pp[h];
    }
  }
}

// ---------------- launch ----------------

extern "C" void kernel_launch(void* const* d_in, const int* in_sizes, int n_in,
                              void* d_out, int out_size, void* d_ws, size_t ws_size,
                              hipStream_t stream) {
  const float* X  = (const float*)d_in[0];
  const int*   sg = (const int*)d_in[1];
  const float* W1 = (const float*)d_in[2];
  const float* b1 = (const float*)d_in[3];
  const float* W2 = (const float*)d_in[4];
  const float* b2 = (const float*)d_in[5];
  const float* W3 = (const float*)d_in[6];
  const float* b3 = (const float*)d_in[7];
  const float* Wr = (const float*)d_in[8];
  const float* br = (const float*)d_in[9];
  const float* Wk = (const float*)d_in[10];
  const float* Wq = (const float*)d_in[11];
  float* out = (float*)d_out;

  const size_t szW1T  = 512 * 128 * 2;
  const size_t szWT   = 512 * 512 * 2;
  const size_t szWeff = 640 * 8 * 4;
  const size_t szCSum = NSEG * 512 * 4;
  const size_t szCCnt = NSEG * 4;
  const size_t fixed  = szW1T + 3 * szWT + szWeff + szCSum + szCCnt;

  int CH = 0;
  const int cands[6] = {131072, 65536, 32768, 16384, 8192, 4096};
  for (int i = 0; i < 6; ++i) {
    const size_t need = fixed + 2 * (size_t)cands[i] * 512 * 2;  // z + g ping-pong
    if (need <= ws_size) { CH = cands[i]; break; }
  }
  if (CH == 0) CH = 4096;

  char* p = (char*)d_ws;
  ushortT* W1T  = (ushortT*)p; p += szW1T;
  ushortT* W2T  = (ushortT*)p; p += szWT;
  ushortT* W3T  = (ushortT*)p; p += szWT;
  ushortT* WrT  = (ushortT*)p; p += szWT;
  float*   weff = (float*)p;   p += szWeff;
  float*   cSum = (float*)p;   p += szCSum;
  int*     cCnt = (int*)p;     p += szCCnt;
  ushortT* p1   = (ushortT*)p; p += (size_t)CH * 512 * 2;
  ushortT* p2   = (ushortT*)p;

  transpose_bf16_kernel<<<(512 * 128 + 255) / 256, 256, 0, stream>>>(W1, W1T, 128, 512);
  transpose_bf16_kernel<<<(512 * 512 + 255) / 256, 256, 0, stream>>>(W2, W2T, 512, 512);
  transpose_bf16_kernel<<<(512 * 512 + 255) / 256, 256, 0, stream>>>(W3, W3T, 512, 512);
  transpose_bf16_kernel<<<(512 * 512 + 255) / 256, 256, 0, stream>>>(Wr, WrT, 512, 512);
  weff_kernel<<<640, 64, 0, stream>>>(Wk, Wq, weff);
  hipMemsetAsync(cSum, 0, szCSum + szCCnt, stream);

  for (int c0 = 0; c0 < N_TOK; c0 += CH) {
    const int gF = (CH / 4 < 4096) ? CH / 4 : 4096;
    fused_chain_kernel<<<CH / 128, 512, 0, stream>>>(X + (size_t)c0 * 128,
                                                     W1T, b1, W2T, b2, W3T, b3, WrT, p2);
    scan_kernel<<<NSEG, 256, 0, stream>>>(p2, p1, sg, br, cSum, cCnt, c0, CH);
    final_kernel<<<gF, 256, 0, stream>>>(X + (size_t)c0 * 128, p1, weff,
                                         out + (size_t)c0 * 8, CH);
  }
}